// Round 4
// baseline (72.130 us; speedup 1.0000x reference)
//
#include <hip/hip_runtime.h>

#define HALO 5
#define SM_H 42        // halo rows per tile
#define BATCH 16
#define CH 3
#define H 512
#define W 512
#define HW (H*W)
#define NBLOCKS 4096

__global__ __launch_bounds__(256, 4) void ssim_tile_kernel(
    const float* __restrict__ pred, const float* __restrict__ gt,
    float* __restrict__ partial)
{
    // Transposed h-sum planes, [x=0..31][y=0..41(+pad)].
    // abcdT: y-stride 43 float4 (odd) -> lane stride 172 floats == 12 mod 32:
    //   quad rotation 3x mod 8 -> conflict-free b128 reads AND writes.
    // eT: y-stride 44 floats (= 4*11) == 12 mod 32: same property.
    __shared__ float4 abcdT[32][43];   // 22.0 KB
    __shared__ float  eT[32][44];      //  5.6 KB
    __shared__ float red[4];

    const int tid = threadIdx.x;
    const int bid = (blockIdx.x & 7) * (NBLOCKS / 8) + (blockIdx.x >> 3); // XCD chunks
    const int b  = bid >> 8;
    const int ty = (bid >> 4) & 15;
    const int tx = bid & 15;

    const float* __restrict__ pb = pred + (size_t)b * (CH * HW);
    const float* __restrict__ gb = gt   + (size_t)b * (CH * HW);

    // ---- h-phase: 168 tasks; lanes grouped 4-per-row for load locality ----
    if (tid < SM_H * 4) {
        const int r   = tid >> 2;        // halo row 0..41
        const int run = tid & 3;         // 8-output run
        const int gy  = (ty << 5) - HALO + r;
        const int g00 = (tx << 5) + (run << 3) - 8;  // 16B-aligned span start
        float ha[8], hb[8], hc[8], hd[8], he[8];
        #pragma unroll
        for (int j = 0; j < 8; ++j) { ha[j]=0.f; hb[j]=0.f; hc[j]=0.f; hd[j]=0.f; he[j]=0.f; }

        if ((unsigned)gy < H) {
            const bool interior = (g00 >= 0) && (g00 + 23 < W);
            #pragma unroll
            for (int ch = 0; ch < CH; ++ch) {
                const float* __restrict__ prow = pb + ch * HW + gy * W;
                const float* __restrict__ grow = gb + ch * HW + gy * W;
                float p[24], g[24];
                if (interior) {
                    #pragma unroll
                    for (int k = 0; k < 6; ++k) {
                        const float4 P = *(const float4*)(prow + g00 + 4 * k);
                        const float4 G = *(const float4*)(grow + g00 + 4 * k);
                        p[4*k+0]=P.x; p[4*k+1]=P.y; p[4*k+2]=P.z; p[4*k+3]=P.w;
                        g[4*k+0]=G.x; g[4*k+1]=G.y; g[4*k+2]=G.z; g[4*k+3]=G.w;
                    }
                } else {
                    #pragma unroll
                    for (int j = 0; j < 24; ++j) {
                        const int col = g00 + j;
                        const bool in = (unsigned)col < W;
                        p[j] = in ? prow[col] : 0.f;
                        g[j] = in ? grow[col] : 0.f;
                    }
                }
                // 11-tap window for output j sits at span indices j+3 .. j+13
                float wa=0.f, wb=0.f, wc=0.f, wd=0.f, we=0.f;
                #pragma unroll
                for (int j = 3; j < 14; ++j) {
                    wa += p[j]; wb += g[j];
                    wc = fmaf(p[j], p[j], wc);
                    wd = fmaf(g[j], g[j], wd);
                    we = fmaf(p[j], g[j], we);
                }
                ha[0]+=wa; hb[0]+=wb; hc[0]+=wc; hd[0]+=wd; he[0]+=we;
                #pragma unroll
                for (int s = 1; s < 8; ++s) {
                    const float pl=p[13+s], gl_=g[13+s], pt=p[2+s], gt_=g[2+s];
                    wa += pl - pt;
                    wb += gl_ - gt_;
                    wc = fmaf(pl, pl, wc);  wc = fmaf(-pt, pt, wc);
                    wd = fmaf(gl_, gl_, wd); wd = fmaf(-gt_, gt_, wd);
                    we = fmaf(pl, gl_, we); we = fmaf(-pt, gt_, we);
                    ha[s]+=wa; hb[s]+=wb; hc[s]+=wc; hd[s]+=wd; he[s]+=we;
                }
            }
        }
        const int xbase = run << 3;
        #pragma unroll
        for (int j = 0; j < 8; ++j) {
            abcdT[xbase + j][r] = make_float4(ha[j], hb[j], hc[j], hd[j]);
            eT[xbase + j][r] = he[j];
        }
    }
    __syncthreads();

    // ---- v-phase: thread (x, yr) -> output rows 4yr..4yr+3 at column x ----
    const int x  = tid & 31;
    const int yr = tid >> 5;
    float4 v[14];
    #pragma unroll
    for (int k = 0; k < 14; ++k) v[k] = abcdT[x][4 * yr + k];
    float ev[16];
    #pragma unroll
    for (int k = 0; k < 4; ++k) {
        const float4 u = *(const float4*)&eT[x][4 * yr + 4 * k];
        ev[4*k]=u.x; ev[4*k+1]=u.y; ev[4*k+2]=u.z; ev[4*k+3]=u.w;
    }
    float sa=0.f, sb=0.f, sc=0.f, sd=0.f, se=0.f;
    #pragma unroll
    for (int k = 0; k < 11; ++k) {
        sa += v[k].x; sb += v[k].y; sc += v[k].z; sd += v[k].w; se += ev[k];
    }
    const float inv_n = 1.0f/363.0f, inv_nm1 = 1.0f/362.0f;
    const float c1 = 1e-4f, c2 = 9e-4f;
    float local = 0.f;
    #pragma unroll
    for (int s = 0; s < 4; ++s) {
        if (s > 0) {
            sa += v[10+s].x - v[s-1].x;
            sb += v[10+s].y - v[s-1].y;
            sc += v[10+s].z - v[s-1].z;
            sd += v[10+s].w - v[s-1].w;
            se += ev[10+s]  - ev[s-1];
        }
        const float mu_p  = sa * inv_n;
        const float mu_g  = sb * inv_n;
        const float var_p = (sc - sa * mu_p) * inv_nm1;
        const float var_g = (sd - sb * mu_g) * inv_nm1;
        const float cov   = (se - sa * mu_g) * inv_n;
        const float num = (2.f * mu_p * mu_g + c1) * (2.f * cov + c2);
        const float den = (mu_p * mu_p + mu_g * mu_g + c1) * (var_p + var_g + c2);
        local += num / (den + 1e-8f);
    }

    // ---- block reduce ----
    #pragma unroll
    for (int off = 32; off > 0; off >>= 1) local += __shfl_down(local, off);
    if ((tid & 63) == 0) red[tid >> 6] = local;
    __syncthreads();
    if (tid == 0) partial[bid] = red[0] + red[1] + red[2] + red[3];
}

__global__ __launch_bounds__(256) void ssim_final_reduce(
    const float* __restrict__ partial, float* __restrict__ out)
{
    __shared__ float red[4];
    const int tid = threadIdx.x;
    float s = 0.f;
    for (int i = tid; i < NBLOCKS; i += 256) s += partial[i];
    #pragma unroll
    for (int off = 32; off > 0; off >>= 1) s += __shfl_down(s, off);
    if ((tid & 63) == 0) red[tid >> 6] = s;
    __syncthreads();
    if (tid == 0) {
        const float total = red[0] + red[1] + red[2] + red[3];
        out[0] = 1.0f - total * (1.0f / (float)(BATCH * H * W));
    }
}

extern "C" void kernel_launch(void* const* d_in, const int* in_sizes, int n_in,
                              void* d_out, int out_size, void* d_ws, size_t ws_size,
                              hipStream_t stream) {
    const float* pred = (const float*)d_in[0];
    const float* gt   = (const float*)d_in[1];
    float* out        = (float*)d_out;
    float* partial    = (float*)d_ws;

    ssim_tile_kernel<<<NBLOCKS, 256, 0, stream>>>(pred, gt, partial);
    ssim_final_reduce<<<1, 256, 0, stream>>>(partial, out);
}

// Round 5
// 44.625 us; speedup vs baseline: 1.6164x; 1.6164x over previous
//
#include <hip/hip_runtime.h>

#define HALO 5
#define SM_H 42        // halo rows/cols per 32x32 tile
#define PSTR 43        // plane row stride in float4 units: 172 floats == 12 mod 32 banks
#define BATCH 16
#define CH 3
#define H 512
#define W 512
#define HW (H*W)
#define NBLOCKS 4096

__global__ __launch_bounds__(256, 5) void ssim_tile_kernel(
    const float* __restrict__ pred, const float* __restrict__ gt,
    float* __restrict__ partial)
{
    // ONE float4 plane, two lives (aliased across a barrier):
    //  Phase A: per-pixel channel-reduced (sum_p, sum_g, sum_pp+gg, sum_pg),
    //           indexed [r=0..41][sc=0..41]  (sc = halo col)
    //  Phase B: transposed horizontal box sums, indexed [x=0..31][y=0..41]
    __shared__ float4 plane[SM_H][PSTR];   // 28.9 KB
    __shared__ float red[4];

    const int tid = threadIdx.x;
    const int bid = (blockIdx.x & 7) * (NBLOCKS / 8) + (blockIdx.x >> 3); // XCD chunks
    const int b  = bid >> 8;
    const int ty = (bid >> 4) & 15;
    const int tx = bid & 15;

    const float* __restrict__ pb = pred + (size_t)b * (CH * HW);
    const float* __restrict__ gb = gt   + (size_t)b * (CH * HW);

    // ---- Stage 1: 504 tasks = float4 slot f (0..11) x halo row r (0..41) ----
    // Aligned span [32tx-8, 32tx+40) covers halo cols [32tx-5, 32tx+37).
    // Lanes are row-major (consecutive lanes -> consecutive rows): LDS writes
    // stride 172 floats == 12 mod 32 -> 2-way max (free).
    #pragma unroll
    for (int t = 0; t < 2; ++t) {
        const int task = tid + t * 256;
        if (task < 504) {
            const int r  = task % SM_H;
            const int f  = task / SM_H;
            const int gy = (ty << 5) - HALO + r;
            const int gx0 = (tx << 5) - 8 + (f << 2);
            float4 q0 = make_float4(0.f,0.f,0.f,0.f);
            float4 q1 = q0, q2 = q0, q3 = q0;
            if ((unsigned)gy < H) {
                const bool interior = (gx0 >= 0) && (gx0 + 3 < W);
                #pragma unroll
                for (int ch = 0; ch < CH; ++ch) {
                    const float* __restrict__ prow = pb + ch * HW + gy * W;
                    const float* __restrict__ grow = gb + ch * HW + gy * W;
                    float p0,p1,p2,p3, g0,g1,g2,g3;
                    if (interior) {
                        const float4 P = *(const float4*)(prow + gx0);
                        const float4 G = *(const float4*)(grow + gx0);
                        p0=P.x; p1=P.y; p2=P.z; p3=P.w;
                        g0=G.x; g1=G.y; g2=G.z; g3=G.w;
                    } else {
                        p0 = ((unsigned)(gx0+0) < W) ? prow[gx0+0] : 0.f;
                        p1 = ((unsigned)(gx0+1) < W) ? prow[gx0+1] : 0.f;
                        p2 = ((unsigned)(gx0+2) < W) ? prow[gx0+2] : 0.f;
                        p3 = ((unsigned)(gx0+3) < W) ? prow[gx0+3] : 0.f;
                        g0 = ((unsigned)(gx0+0) < W) ? grow[gx0+0] : 0.f;
                        g1 = ((unsigned)(gx0+1) < W) ? grow[gx0+1] : 0.f;
                        g2 = ((unsigned)(gx0+2) < W) ? grow[gx0+2] : 0.f;
                        g3 = ((unsigned)(gx0+3) < W) ? grow[gx0+3] : 0.f;
                    }
                    q0.x += p0; q0.y += g0; q0.z = fmaf(p0,p0,fmaf(g0,g0,q0.z)); q0.w = fmaf(p0,g0,q0.w);
                    q1.x += p1; q1.y += g1; q1.z = fmaf(p1,p1,fmaf(g1,g1,q1.z)); q1.w = fmaf(p1,g1,q1.w);
                    q2.x += p2; q2.y += g2; q2.z = fmaf(p2,p2,fmaf(g2,g2,q2.z)); q2.w = fmaf(p2,g2,q2.w);
                    q3.x += p3; q3.y += g3; q3.z = fmaf(p3,p3,fmaf(g3,g3,q3.z)); q3.w = fmaf(p3,g3,q3.w);
                }
            }
            const int sc0 = (f << 2) - 3;   // halo col of first pixel in the float4
            if ((unsigned)(sc0+0) < SM_H) plane[r][sc0+0] = q0;
            if ((unsigned)(sc0+1) < SM_H) plane[r][sc0+1] = q1;
            if ((unsigned)(sc0+2) < SM_H) plane[r][sc0+2] = q2;
            if ((unsigned)(sc0+3) < SM_H) plane[r][sc0+3] = q3;
        }
    }
    __syncthreads();

    // ---- Stage 2: horizontal 11-tap sliding sums (168 tasks), regs across barrier ----
    float4 hv[8];
    const bool act2 = tid < SM_H * 4;
    int r2 = 0, j0 = 0;
    if (act2) {
        r2 = tid % SM_H;          // consecutive lanes -> consecutive rows
        j0 = (tid / SM_H) << 3;   // output run start: window cols [j0, j0+17]
        float4 v[18];
        #pragma unroll
        for (int k = 0; k < 11; ++k) v[k] = plane[r2][j0 + k];
        float4 w = v[0];
        #pragma unroll
        for (int k = 1; k < 11; ++k) {
            w.x += v[k].x; w.y += v[k].y; w.z += v[k].z; w.w += v[k].w;
        }
        hv[0] = w;
        #pragma unroll
        for (int s = 1; s < 8; ++s) {
            v[10 + s] = plane[r2][j0 + 10 + s];
            w.x += v[10+s].x - v[s-1].x;
            w.y += v[10+s].y - v[s-1].y;
            w.z += v[10+s].z - v[s-1].z;
            w.w += v[10+s].w - v[s-1].w;
            hv[s] = w;
        }
    }
    __syncthreads();
    if (act2) {
        #pragma unroll
        for (int s = 0; s < 8; ++s) plane[j0 + s][r2] = hv[s];  // transposed
    }
    __syncthreads();

    // ---- Stage 3: vertical 11-tap sliding sums + SSIM (4 rows per thread) ----
    const int x  = tid & 31;
    const int yr = tid >> 5;
    float4 v3[14];
    #pragma unroll
    for (int k = 0; k < 14; ++k) v3[k] = plane[x][4 * yr + k];
    float sa = v3[0].x, sb = v3[0].y, sc_ = v3[0].z, se = v3[0].w;
    #pragma unroll
    for (int k = 1; k < 11; ++k) {
        sa += v3[k].x; sb += v3[k].y; sc_ += v3[k].z; se += v3[k].w;
    }
    const float inv_n = 1.0f/363.0f, inv_nm1 = 1.0f/362.0f;
    const float c1 = 1e-4f, c2 = 9e-4f;
    float local = 0.f;
    #pragma unroll
    for (int s = 0; s < 4; ++s) {
        if (s > 0) {
            sa  += v3[10+s].x - v3[s-1].x;
            sb  += v3[10+s].y - v3[s-1].y;
            sc_ += v3[10+s].z - v3[s-1].z;
            se  += v3[10+s].w - v3[s-1].w;
        }
        const float mu_p = sa * inv_n;
        const float mu_g = sb * inv_n;
        const float varsum = (sc_ - sa * mu_p - sb * mu_g) * inv_nm1;
        const float cov    = (se - sa * mu_g) * inv_n;
        const float num = (2.f * mu_p * mu_g + c1) * (2.f * cov + c2);
        const float den = (mu_p * mu_p + mu_g * mu_g + c1) * (varsum + c2);
        local += num / (den + 1e-8f);
    }

    // ---- block reduce ----
    #pragma unroll
    for (int off = 32; off > 0; off >>= 1) local += __shfl_down(local, off);
    if ((tid & 63) == 0) red[tid >> 6] = local;
    __syncthreads();
    if (tid == 0) partial[bid] = red[0] + red[1] + red[2] + red[3];
}

__global__ __launch_bounds__(256) void ssim_final_reduce(
    const float* __restrict__ partial, float* __restrict__ out)
{
    __shared__ float red[4];
    const int tid = threadIdx.x;
    float s = 0.f;
    for (int i = tid; i < NBLOCKS; i += 256) s += partial[i];
    #pragma unroll
    for (int off = 32; off > 0; off >>= 1) s += __shfl_down(s, off);
    if ((tid & 63) == 0) red[tid >> 6] = s;
    __syncthreads();
    if (tid == 0) {
        const float total = red[0] + red[1] + red[2] + red[3];
        out[0] = 1.0f - total * (1.0f / (float)(BATCH * H * W));
    }
}

extern "C" void kernel_launch(void* const* d_in, const int* in_sizes, int n_in,
                              void* d_out, int out_size, void* d_ws, size_t ws_size,
                              hipStream_t stream) {
    const float* pred = (const float*)d_in[0];
    const float* gt   = (const float*)d_in[1];
    float* out        = (float*)d_out;
    float* partial    = (float*)d_ws;

    ssim_tile_kernel<<<NBLOCKS, 256, 0, stream>>>(pred, gt, partial);
    ssim_final_reduce<<<1, 256, 0, stream>>>(partial, out);
}